// Round 15
// baseline (407.974 us; speedup 1.0000x reference)
//
#include <hip/hip_runtime.h>

#define NG 8000
#define NG3 24000
#define TS 1440
#define NOUT 32
#define LENFT 72
#define DTC (1.0f/24.0f)
#define NEARZEROC 1e-5f

// gfx950 hardware transcendentals (base-2). Pure ops -> non-volatile asm (CSE ok).
__device__ __forceinline__ float fexp2(float x) {
  float r; asm("v_exp_f32 %0, %1" : "=v"(r) : "v"(x)); return r;
}
__device__ __forceinline__ float flog2(float x) {
  float r; asm("v_log_f32 %0, %1" : "=v"(r) : "v"(x)); return r;
}

typedef const void __attribute__((address_space(1))) gas_void;
typedef void __attribute__((address_space(3)))       las_void;

// ---------------------------------------------------------------------------
// Kernel 1: per-cell constants + normalized routing weights
// ---------------------------------------------------------------------------
__global__ __launch_bounds__(256) void precompute_kernel(
    const float* __restrict__ p1, const float* __restrict__ p2,
    const float* __restrict__ ac_all,
    float* __restrict__ Cst,   // 16 * NG floats (SoA)
    float* __restrict__ W)     // LENFT * NG floats (k-major)
{
  int n = blockIdx.x * 256 + threadIdx.x;
  if (n >= NG) return;
  const float* r = p1 + n * 19;
  float BETA   = 1.0f   + r[0]  * 5.0f;
  float FC     = 50.0f  + r[1]  * 950.0f;
  float K0     = 0.05f  + r[2]  * 0.85f;
  float K1     = 0.01f  + r[3]  * 0.49f;
  float K2     = 0.001f + r[4]  * 0.199f;
  float LP     = 0.2f   + r[5]  * 0.8f;
  float PERC   =          r[6]  * 10.0f;
  float UZL    =          r[7]  * 100.0f;
  float TT     = -2.5f  + r[8]  * 5.0f;
  float CFMAX  = 0.5f   + r[9]  * 9.5f;
  float CFR    =          r[10] * 0.1f;
  float CWH    =          r[11] * 0.2f;
  float BETAET = 0.3f   + r[12] * 4.7f;
  float Cpar   =          r[13];
  float RT     =          r[14] * 20.0f;
  float AC     =          r[15] * 2500.0f;
  float F0     = 120.0f + r[16] * 2760.0f;
  float FMIN   =          r[17];
  float ALPHA  = 0.5f   + r[18] * 4.5f;

  float ac  = ac_all[n];
  float fmx = DTC * F0 * (FMIN + (1.0f - FMIN) * expf(-powf(ac / (AC + 1.0f), 1.0f / ALPHA)));

  Cst[ 0*NG+n] = TT;            Cst[ 1*NG+n] = CFMAX * DTC;
  Cst[ 2*NG+n] = CFR*CFMAX*DTC; Cst[ 3*NG+n] = CWH;
  Cst[ 4*NG+n] = fmx;           Cst[ 5*NG+n] = 1.0f / FC;
  Cst[ 6*NG+n] = BETA;          Cst[ 7*NG+n] = FC;
  Cst[ 8*NG+n] = Cpar;          Cst[ 9*NG+n] = 1.0f / (LP * FC);
  Cst[10*NG+n] = BETAET;        Cst[11*NG+n] = PERC * DTC;
  Cst[12*NG+n] = K0 * DTC;      Cst[13*NG+n] = UZL;
  Cst[14*NG+n] = K1 * DTC;      Cst[15*NG+n] = K2 * DTC;

  // routing weights (gamma kernel), normalized
  float a   = fmaxf(p2[n*3+0] * 5.0f,  0.01f);
  float b   = fmaxf(p2[n*3+1] * 12.0f, 0.01f);
  float lag = p2[n*3+2] * 48.0f + RT;
  float am1 = a - 1.0f, invb = 1.0f / b;
  float sum = 0.0f;
  for (int k = 0; k < LENFT; k++) {
    float s  = (k + 0.5f) - lag;
    float sm = fmaxf(s, 1e-6f);
    float wv = (s > 0.0f) ? expf(am1 * logf(sm) - sm * invb) : 0.0f;
    sum += wv;
  }
  float inv = 1.0f / (sum + 1e-8f);
  for (int k = 0; k < LENFT; k++) {
    float s  = (k + 0.5f) - lag;
    float sm = fmaxf(s, 1e-6f);
    float wv = (s > 0.0f) ? expf(am1 * logf(sm) - sm * invb) : 0.0f;
    W[k*NG + n] = wv * inv;
  }
}

// ---------------------------------------------------------------------------
// Kernel 2: sequential HBV scan — snow/soil chain decoupling.
// r14 calibration: 363 cyc/step = ~130 issue + ~230 chain stall. The HBV
// step factors into an independent SNOW chain (SP,MW -> infil/qie; short,
// no transcendentals) and a SOIL chain (SM,SUZ,SLZ; all 4 transcendentals).
// Pipeline loads 2 blocks ahead, snow 1 block ahead, soil current; each
// basic block pairs {snow8(next), soil8(cur)} so the scheduler can slot
// snow ops into soil-chain stalls. (Unlike r13's failed ILP-2: only +24
// regs, and independence is structural, not alias-analysis-dependent.)
// ---------------------------------------------------------------------------
struct HbvConst {
  float TT, CFMAXDT, CFRDT, CWH, FMX, IFC, BETA, FC, C, ILF, BETAET,
        PERCDT, K0DT, UZL, K1DT, K2DT;
};

__device__ __forceinline__ void load_const(const float* __restrict__ Cst,
                                           int n, HbvConst& c) {
  c.TT    =Cst[ 0*NG+n]; c.CFMAXDT=Cst[ 1*NG+n]; c.CFRDT =Cst[ 2*NG+n];
  c.CWH   =Cst[ 3*NG+n]; c.FMX    =Cst[ 4*NG+n]; c.IFC   =Cst[ 5*NG+n];
  c.BETA  =Cst[ 6*NG+n]; c.FC     =Cst[ 7*NG+n]; c.C     =Cst[ 8*NG+n];
  c.ILF   =Cst[ 9*NG+n]; c.BETAET =Cst[10*NG+n]; c.PERCDT=Cst[11*NG+n];
  c.K0DT  =Cst[12*NG+n]; c.UZL    =Cst[13*NG+n]; c.K1DT  =Cst[14*NG+n];
  c.K2DT  =Cst[15*NG+n];
}

// loads with uniform (scalar) base per step + per-lane offset 3n
#define LOADU8(A, T0)                                                         \
  { _Pragma("unroll")                                                         \
    for (int i_ = 0; i_ < 8; i_++) {                                          \
      const float* b_ = x + (size_t)((T0) + i_) * NG3;                        \
      A[i_] = *reinterpret_cast<const float3*>(b_ + 3 * n);                   \
    } }

__global__ __launch_bounds__(64, 1) void scan_kernel(
    const float* __restrict__ x, const float* __restrict__ Cst,
    float* __restrict__ Q)
{
  int n = blockIdx.x * 64 + threadIdx.x;      // NG = 125*64 exact
  HbvConst c; load_const(Cst, n, c);
  float SP=1e-3f, MW=1e-3f, SM=1e-3f, SUZ=1e-3f, SLZ=1e-3f;

  // snow chain: consumes raw (P,T), produces infil/qie; PET passed through.
  auto snow8 = [&](const float3* buf, float* inf, float* qie, float* pet) {
    #pragma unroll
    for (int i = 0; i < 8; i++) {
      float P = buf[i].x, Tm = buf[i].y;
      bool  w    = Tm >= c.TT;
      float dT   = Tm - c.TT;
      float rain = w ? P : 0.0f;
      SP += P - rain;
      float k  = w ? c.CFMAXDT : c.CFRDT;
      float tr = __builtin_amdgcn_fmed3f(k * dT, -MW, SP);   // fused melt/refr
      MW += tr; SP -= tr;
      float tos = fmaxf(MW - c.CWH * SP, 0.0f);
      MW -= tos;
      float win = rain + tos;
      float nf  = fminf(win, c.FMX);
      inf[i] = nf; qie[i] = win - nf; pet[i] = buf[i].z;
    }
  };
  // soil chain: all transcendentals; the critical path.
  auto soil8 = [&](const float* inf, const float* qie, const float* pet, int tb) {
    #pragma unroll
    for (int i = 0; i < 8; i++) {
      float nf   = inf[i];
      float sw   = fminf(fexp2(c.BETA * flog2(SM * c.IFC)), 1.0f);
      float rech = nf * sw;
      SM += nf - rech;
      float exc = fmaxf(SM - c.FC, 0.0f);
      SM -= exc;
      float u   = fmaxf(1.0f - SM * c.IFC, 0.0f);   // cap min(SLZ,.) dead: C*u<=1
      float cap = c.C * SLZ * u;
      SM += cap; SLZ -= cap;
      float ef = fminf(fexp2(c.BETAET * flog2(SM * c.ILF)), 1.0f);
      SM = fmaxf(SM - pet[i] * ef, NEARZEROC);       // et min folded into clamp
      SUZ += rech + exc;
      float perc = fminf(SUZ, c.PERCDT);
      SUZ -= perc;
      float q0 = c.K0DT * fmaxf(SUZ - c.UZL, 0.0f);
      SUZ -= q0;
      float q1 = c.K1DT * SUZ;
      SUZ -= q1;
      SLZ += perc;
      float q2 = c.K2DT * SLZ;
      SLZ -= q2;
      (Q + (size_t)(tb + i) * NG)[n] = qie[i] + q0 + q1 + q2;
    }
  };

  float3 bufA[8], bufB[8];
  float infA[8], qieA[8], petA[8], infB[8], qieB[8], petB[8];

  // prologue: loads 2 blocks deep, snow 1 block deep
  LOADU8(bufA, 0);
  snow8(bufA, infA, qieA, petA);
  LOADU8(bufB, 8);

  for (int tb = 0; tb < TS; tb += 16) {
    if (tb + 16 < TS) LOADU8(bufA, tb + 16);   // load block j+2
    snow8(bufB, infB, qieB, petB);             // snow block j+1   } same BB:
    soil8(infA, qieA, petA, tb);               // soil block j     } interleave
    if (tb + 24 < TS) LOADU8(bufB, tb + 24);   // load block j+3
    snow8(bufA, infA, qieA, petA);             // snow block j+2 (stale-safe at end)
    soil8(infB, qieB, petB, tb + 8);           // soil block j+1
  }
}

// ---------------------------------------------------------------------------
// Kernel 3: fused routing FIR (72 taps) + partial einsum — UNCHANGED (r12).
// gll staging, async stage(sub+1) under einsum, bijective XCD chunk swizzle.
// ---------------------------------------------------------------------------
#define TTILE 48
#define NTILES_T 30          // 1440 / 48
#define NSPLIT 25
#define SUBS 5               // subtiles per split (25*5*64 = 8000)
#define QROWS (TTILE + 71)   // 119
#define NWG (NTILES_T * NSPLIT)  // 750

__global__ __launch_bounds__(256, 2) void route_kernel(
    const float* __restrict__ Q, const float* __restrict__ W,
    const float* __restrict__ topo, const float* __restrict__ areas,
    float* __restrict__ Par)   // [NSPLIT][TS][NOUT]
{
  __shared__ float Qs[QROWS][64];   // 30.5 KB
  __shared__ float Ws[LENFT][64];   // 18.4 KB
  __shared__ float Rs[TTILE][68];   // 13.1 KB (pad 68: float4-aligned rows)

  int bid  = blockIdx.x;
  int xcd  = bid & 7, pos = bid >> 3;
  const int q = NWG / 8, r = NWG % 8;              // 93, 6
  int wgid = ((xcd < r) ? xcd * (q + 1) : r * (q + 1) + (xcd - r) * q) + pos;
  int tile  = wgid % NTILES_T;      // consecutive wgid -> consecutive tiles
  int split = wgid / NTILES_T;
  int t0    = tile * TTILE;
  int tid   = threadIdx.x;
  int wid   = tid >> 6, lane = tid & 63;

  int nn = tid & 63;                // conv: cell within subtile
  int tc = wid * 12;                // conv: 12 consecutive t-rows
  int oe = tid & 31;                // einsum: outlet
  int te = (tid >> 5) * 6;          // einsum: 6 consecutive t-rows

  auto stage = [&](int sub) {
    int n0 = (split * SUBS + sub) * 64;
    for (int rr = wid; rr < QROWS; rr += 4) {
      int t = t0 - 71 + rr;
      if (t >= 0)
        __builtin_amdgcn_global_load_lds(
            (gas_void*)(Q + (size_t)t * NG + n0 + lane),
            (las_void*)(&Qs[rr][0]), 4, 0, 0);
      else
        Qs[rr][lane] = 0.0f;
    }
    for (int k = wid; k < LENFT; k += 4)
      __builtin_amdgcn_global_load_lds(
          (gas_void*)(W + (size_t)k * NG + n0 + lane),
          (las_void*)(&Ws[k][0]), 4, 0, 0);
  };

  float acc_out[6] = {0.f, 0.f, 0.f, 0.f, 0.f, 0.f};

  stage(0);
  for (int sub = 0; sub < SUBS; sub++) {
    int n0 = (split * SUBS + sub) * 64;

    float4 Greg[16];
    #pragma unroll
    for (int g4 = 0; g4 < 16; g4++) {
      float4 tv = *reinterpret_cast<const float4*>(&topo[oe * NG + n0 + g4 * 4]);
      float4 av = *reinterpret_cast<const float4*>(&areas[n0 + g4 * 4]);
      Greg[g4] = make_float4(tv.x * av.x, tv.y * av.y, tv.z * av.z, tv.w * av.w);
    }

    __syncthreads();   // staging(sub) complete

    float acc[12];
    float qwin[12];
    #pragma unroll
    for (int i = 0; i < 12; i++) { acc[i] = 0.0f; qwin[i] = Qs[tc + i][nn]; }
    #pragma unroll
    for (int kk = 0; kk < LENFT; kk++) {
      float w = Ws[71 - kk][nn];
      #pragma unroll
      for (int i = 0; i < 12; i++) acc[i] += w * qwin[i];
      #pragma unroll
      for (int i = 0; i < 11; i++) qwin[i] = qwin[i + 1];
      if (kk < 71) qwin[11] = Qs[tc + 12 + kk][nn];
    }
    #pragma unroll
    for (int i = 0; i < 12; i++) Rs[tc + i][nn] = acc[i];
    __syncthreads();   // Rs visible; Qs/Ws reads done

    if (sub + 1 < SUBS) stage(sub + 1);   // overlaps with einsum below

    #pragma unroll
    for (int g4 = 0; g4 < 16; g4++) {
      float4 g = Greg[g4];
      #pragma unroll
      for (int p = 0; p < 6; p++) {
        float4 rv = *reinterpret_cast<const float4*>(&Rs[te + p][g4 * 4]);
        acc_out[p] += rv.x * g.x + rv.y * g.y + rv.z * g.z + rv.w * g.w;
      }
    }
  }

  #pragma unroll
  for (int p = 0; p < 6; p++) {
    int tg = t0 + te + p;           // always < 1440 (30*48 exact)
    Par[(split * TS + tg) * NOUT + oe] = acc_out[p];
  }
}

// ---------------------------------------------------------------------------
// Kernel 4: reduce partials over the 25 n-splits
// ---------------------------------------------------------------------------
__global__ __launch_bounds__(256) void reduce_kernel(
    const float* __restrict__ Par, float* __restrict__ out)
{
  int i = blockIdx.x * 256 + threadIdx.x;
  if (i < TS * NOUT) {
    float s = 0.0f;
    #pragma unroll
    for (int sp = 0; sp < NSPLIT; sp++) s += Par[sp * (TS * NOUT) + i];
    out[i] = s;
  }
}

// ---------------------------------------------------------------------------
extern "C" void kernel_launch(void* const* d_in, const int* in_sizes, int n_in,
                              void* d_out, int out_size, void* d_ws, size_t ws_size,
                              hipStream_t stream)
{
  const float* x_phy  = (const float*)d_in[0];
  const float* ac_all = (const float*)d_in[1];
  // d_in[2] = elev_all (unused by reference)
  const float* topo   = (const float*)d_in[3];
  const float* areas  = (const float*)d_in[4];
  const float* p1     = (const float*)d_in[5];
  const float* p2     = (const float*)d_in[6];
  float* out = (float*)d_out;

  char* ws = (char*)d_ws;
  float* Q   = (float*)(ws);                                  // 46,080,000 B
  float* W   = (float*)(ws + 46080000);                       //  2,304,000 B
  float* Cst = (float*)(ws + 46080000 + 2304000);             //    512,000 B
  float* Par = (float*)(ws + 46080000 + 2304000 + 512000);    //  4,608,000 B

  hipLaunchKernelGGL(precompute_kernel, dim3(32), dim3(256), 0, stream,
                     p1, p2, ac_all, Cst, W);
  hipLaunchKernelGGL(scan_kernel, dim3(NG / 64), dim3(64), 0, stream,
                     x_phy, Cst, Q);
  hipLaunchKernelGGL(route_kernel, dim3(NWG), dim3(256), 0, stream,
                     Q, W, topo, areas, Par);
  hipLaunchKernelGGL(reduce_kernel, dim3((TS * NOUT + 255) / 256), dim3(256), 0, stream,
                     Par, out);
}

// Round 16
// 296.367 us; speedup vs baseline: 1.3766x; 1.3766x over previous
//
#include <hip/hip_runtime.h>

#define NG 8000
#define NG3 24000
#define TS 1440
#define NOUT 32
#define LENFT 72
#define DTC (1.0f/24.0f)
#define NEARZEROC 1e-5f

// gfx950 hardware transcendentals (base-2). Pure ops -> non-volatile asm (CSE ok).
__device__ __forceinline__ float fexp2(float x) {
  float r; asm("v_exp_f32 %0, %1" : "=v"(r) : "v"(x)); return r;
}
__device__ __forceinline__ float flog2(float x) {
  float r; asm("v_log_f32 %0, %1" : "=v"(r) : "v"(x)); return r;
}

typedef const void __attribute__((address_space(1))) gas_void;
typedef void __attribute__((address_space(3)))       las_void;

// ---------------------------------------------------------------------------
// Kernel 1: per-cell constants + normalized routing weights
// ---------------------------------------------------------------------------
__global__ __launch_bounds__(256) void precompute_kernel(
    const float* __restrict__ p1, const float* __restrict__ p2,
    const float* __restrict__ ac_all,
    float* __restrict__ Cst,   // 16 * NG floats (SoA)
    float* __restrict__ W)     // LENFT * NG floats (k-major)
{
  int n = blockIdx.x * 256 + threadIdx.x;
  if (n >= NG) return;
  const float* r = p1 + n * 19;
  float BETA   = 1.0f   + r[0]  * 5.0f;
  float FC     = 50.0f  + r[1]  * 950.0f;
  float K0     = 0.05f  + r[2]  * 0.85f;
  float K1     = 0.01f  + r[3]  * 0.49f;
  float K2     = 0.001f + r[4]  * 0.199f;
  float LP     = 0.2f   + r[5]  * 0.8f;
  float PERC   =          r[6]  * 10.0f;
  float UZL    =          r[7]  * 100.0f;
  float TT     = -2.5f  + r[8]  * 5.0f;
  float CFMAX  = 0.5f   + r[9]  * 9.5f;
  float CFR    =          r[10] * 0.1f;
  float CWH    =          r[11] * 0.2f;
  float BETAET = 0.3f   + r[12] * 4.7f;
  float Cpar   =          r[13];
  float RT     =          r[14] * 20.0f;
  float AC     =          r[15] * 2500.0f;
  float F0     = 120.0f + r[16] * 2760.0f;
  float FMIN   =          r[17];
  float ALPHA  = 0.5f   + r[18] * 4.5f;

  float ac  = ac_all[n];
  float fmx = DTC * F0 * (FMIN + (1.0f - FMIN) * expf(-powf(ac / (AC + 1.0f), 1.0f / ALPHA)));

  Cst[ 0*NG+n] = TT;            Cst[ 1*NG+n] = CFMAX * DTC;
  Cst[ 2*NG+n] = CFR*CFMAX*DTC; Cst[ 3*NG+n] = CWH;
  Cst[ 4*NG+n] = fmx;           Cst[ 5*NG+n] = 1.0f / FC;
  Cst[ 6*NG+n] = BETA;          Cst[ 7*NG+n] = FC;
  Cst[ 8*NG+n] = Cpar;          Cst[ 9*NG+n] = 1.0f / (LP * FC);
  Cst[10*NG+n] = BETAET;        Cst[11*NG+n] = PERC * DTC;
  Cst[12*NG+n] = K0 * DTC;      Cst[13*NG+n] = UZL;
  Cst[14*NG+n] = K1 * DTC;      Cst[15*NG+n] = K2 * DTC;

  // routing weights (gamma kernel), normalized
  float a   = fmaxf(p2[n*3+0] * 5.0f,  0.01f);
  float b   = fmaxf(p2[n*3+1] * 12.0f, 0.01f);
  float lag = p2[n*3+2] * 48.0f + RT;
  float am1 = a - 1.0f, invb = 1.0f / b;
  float sum = 0.0f;
  for (int k = 0; k < LENFT; k++) {
    float s  = (k + 0.5f) - lag;
    float sm = fmaxf(s, 1e-6f);
    float wv = (s > 0.0f) ? expf(am1 * logf(sm) - sm * invb) : 0.0f;
    sum += wv;
  }
  float inv = 1.0f / (sum + 1e-8f);
  for (int k = 0; k < LENFT; k++) {
    float s  = (k + 0.5f) - lag;
    float sm = fmaxf(s, 1e-6f);
    float wv = (s > 0.0f) ? expf(am1 * logf(sm) - sm * invb) : 0.0f;
    W[k*NG + n] = wv * inv;
  }
}

// ---------------------------------------------------------------------------
// Kernel 2: sequential HBV scan. PROVEN FORM (r14: 218 us, VGPR 48).
// 125 blocks x 64 thr, 8-deep float3 register double-buffer, uniform-base
// addressing, exact algebraic trims (fused melt/refr med3; cap min dropped;
// et min folded into eps clamp).
// Failed & abandoned structural attacks (keep for the record):
//   r7 512-thr blocks (16 CUs, per-CU BW floor), r8 ILP-2 sequential,
//   r9 async-LDS ring + counted vmcnt, r13 ILP-2 interleaved (compiler
//   refuses 2-chain regalloc), r15 snow/soil decoupling (schedule degraded).
// ---------------------------------------------------------------------------
struct HbvConst {
  float TT, CFMAXDT, CFRDT, CWH, FMX, IFC, BETA, FC, C, ILF, BETAET,
        PERCDT, K0DT, UZL, K1DT, K2DT;
};

__device__ __forceinline__ void load_const(const float* __restrict__ Cst,
                                           int n, HbvConst& c) {
  c.TT    =Cst[ 0*NG+n]; c.CFMAXDT=Cst[ 1*NG+n]; c.CFRDT =Cst[ 2*NG+n];
  c.CWH   =Cst[ 3*NG+n]; c.FMX    =Cst[ 4*NG+n]; c.IFC   =Cst[ 5*NG+n];
  c.BETA  =Cst[ 6*NG+n]; c.FC     =Cst[ 7*NG+n]; c.C     =Cst[ 8*NG+n];
  c.ILF   =Cst[ 9*NG+n]; c.BETAET =Cst[10*NG+n]; c.PERCDT=Cst[11*NG+n];
  c.K0DT  =Cst[12*NG+n]; c.UZL    =Cst[13*NG+n]; c.K1DT  =Cst[14*NG+n];
  c.K2DT  =Cst[15*NG+n];
}

__device__ __forceinline__ float hbv_step(float P, float Tm, float PET,
    const HbvConst& c, float& SP, float& MW, float& SM, float& SUZ, float& SLZ)
{
  bool  w    = Tm >= c.TT;
  float dT   = Tm - c.TT;
  float rain = w ? P : 0.0f;
  SP += P - rain;
  // fused melt/refr (exact): dT>=0 -> med3 = min(CFMAXDT*dT, SP) = melt;
  // dT<0 -> med3 = max(CFRDT*dT, -MW) = -refr.
  float k  = w ? c.CFMAXDT : c.CFRDT;
  float tr = __builtin_amdgcn_fmed3f(k * dT, -MW, SP);
  MW += tr; SP -= tr;
  float tosoil = fmaxf(MW - c.CWH * SP, 0.0f);
  MW -= tosoil;
  float win   = rain + tosoil;
  float infil = fminf(win, c.FMX);
  float qie   = win - infil;
  float sw    = fminf(fexp2(c.BETA * flog2(SM * c.IFC)), 1.0f);
  float rech  = infil * sw;
  SM += infil - rech;
  float excess = fmaxf(SM - c.FC, 0.0f);
  SM -= excess;
  // cap: outer min(SLZ,.) dead since C*u <= 1
  float u   = fmaxf(1.0f - SM * c.IFC, 0.0f);
  float cap = c.C * SLZ * u;
  SM += cap; SLZ -= cap;
  float ef = fminf(fexp2(c.BETAET * flog2(SM * c.ILF)), 1.0f);
  // et min folded into the eps clamp (exact)
  SM = fmaxf(SM - PET * ef, NEARZEROC);
  SUZ += rech + excess;
  float perc = fminf(SUZ, c.PERCDT);
  SUZ -= perc;
  float q0 = c.K0DT * fmaxf(SUZ - c.UZL, 0.0f);
  SUZ -= q0;
  float q1 = c.K1DT * SUZ;
  SUZ -= q1;
  SLZ += perc;
  float q2 = c.K2DT * SLZ;
  SLZ -= q2;
  return qie + q0 + q1 + q2;
}

// loads with uniform (scalar) base per step + per-lane offset 3n
#define LOADU8(A, T0)                                                         \
  { _Pragma("unroll")                                                         \
    for (int i_ = 0; i_ < 8; i_++) {                                          \
      const float* b_ = x + (size_t)((T0) + i_) * NG3;                        \
      A[i_] = *reinterpret_cast<const float3*>(b_ + 3 * n);                   \
    } }

__global__ __launch_bounds__(64, 1) void scan_kernel(
    const float* __restrict__ x, const float* __restrict__ Cst,
    float* __restrict__ Q)
{
  int n = blockIdx.x * 64 + threadIdx.x;      // NG = 125*64 exact
  HbvConst c; load_const(Cst, n, c);
  float SP=1e-3f, MW=1e-3f, SM=1e-3f, SUZ=1e-3f, SLZ=1e-3f;

  float3 bufA[8], bufB[8];
  LOADU8(bufA, 0);
  for (int tb = 0; tb < TS; tb += 16) {
    LOADU8(bufB, tb + 8);                     // prefetch next 8 steps
    #pragma unroll
    for (int i = 0; i < 8; i++) {
      float* qb = Q + (size_t)(tb + i) * NG;  // uniform base, lane offset n
      qb[n] = hbv_step(bufA[i].x, bufA[i].y, bufA[i].z, c, SP, MW, SM, SUZ, SLZ);
    }
    if (tb + 16 < TS) LOADU8(bufA, tb + 16);
    #pragma unroll
    for (int i = 0; i < 8; i++) {
      float* qb = Q + (size_t)(tb + 8 + i) * NG;
      qb[n] = hbv_step(bufB[i].x, bufB[i].y, bufB[i].z, c, SP, MW, SM, SUZ, SLZ);
    }
  }
}

// ---------------------------------------------------------------------------
// Kernel 3: fused routing FIR (72 taps) + partial einsum — UNCHANGED (r12).
// gll staging, async stage(sub+1) under einsum, bijective XCD chunk swizzle.
// ---------------------------------------------------------------------------
#define TTILE 48
#define NTILES_T 30          // 1440 / 48
#define NSPLIT 25
#define SUBS 5               // subtiles per split (25*5*64 = 8000)
#define QROWS (TTILE + 71)   // 119
#define NWG (NTILES_T * NSPLIT)  // 750

__global__ __launch_bounds__(256, 2) void route_kernel(
    const float* __restrict__ Q, const float* __restrict__ W,
    const float* __restrict__ topo, const float* __restrict__ areas,
    float* __restrict__ Par)   // [NSPLIT][TS][NOUT]
{
  __shared__ float Qs[QROWS][64];   // 30.5 KB
  __shared__ float Ws[LENFT][64];   // 18.4 KB
  __shared__ float Rs[TTILE][68];   // 13.1 KB (pad 68: float4-aligned rows)

  int bid  = blockIdx.x;
  int xcd  = bid & 7, pos = bid >> 3;
  const int q = NWG / 8, r = NWG % 8;              // 93, 6
  int wgid = ((xcd < r) ? xcd * (q + 1) : r * (q + 1) + (xcd - r) * q) + pos;
  int tile  = wgid % NTILES_T;      // consecutive wgid -> consecutive tiles
  int split = wgid / NTILES_T;
  int t0    = tile * TTILE;
  int tid   = threadIdx.x;
  int wid   = tid >> 6, lane = tid & 63;

  int nn = tid & 63;                // conv: cell within subtile
  int tc = wid * 12;                // conv: 12 consecutive t-rows
  int oe = tid & 31;                // einsum: outlet
  int te = (tid >> 5) * 6;          // einsum: 6 consecutive t-rows

  auto stage = [&](int sub) {
    int n0 = (split * SUBS + sub) * 64;
    for (int rr = wid; rr < QROWS; rr += 4) {
      int t = t0 - 71 + rr;
      if (t >= 0)
        __builtin_amdgcn_global_load_lds(
            (gas_void*)(Q + (size_t)t * NG + n0 + lane),
            (las_void*)(&Qs[rr][0]), 4, 0, 0);
      else
        Qs[rr][lane] = 0.0f;
    }
    for (int k = wid; k < LENFT; k += 4)
      __builtin_amdgcn_global_load_lds(
          (gas_void*)(W + (size_t)k * NG + n0 + lane),
          (las_void*)(&Ws[k][0]), 4, 0, 0);
  };

  float acc_out[6] = {0.f, 0.f, 0.f, 0.f, 0.f, 0.f};

  stage(0);
  for (int sub = 0; sub < SUBS; sub++) {
    int n0 = (split * SUBS + sub) * 64;

    float4 Greg[16];
    #pragma unroll
    for (int g4 = 0; g4 < 16; g4++) {
      float4 tv = *reinterpret_cast<const float4*>(&topo[oe * NG + n0 + g4 * 4]);
      float4 av = *reinterpret_cast<const float4*>(&areas[n0 + g4 * 4]);
      Greg[g4] = make_float4(tv.x * av.x, tv.y * av.y, tv.z * av.z, tv.w * av.w);
    }

    __syncthreads();   // staging(sub) complete

    float acc[12];
    float qwin[12];
    #pragma unroll
    for (int i = 0; i < 12; i++) { acc[i] = 0.0f; qwin[i] = Qs[tc + i][nn]; }
    #pragma unroll
    for (int kk = 0; kk < LENFT; kk++) {
      float w = Ws[71 - kk][nn];
      #pragma unroll
      for (int i = 0; i < 12; i++) acc[i] += w * qwin[i];
      #pragma unroll
      for (int i = 0; i < 11; i++) qwin[i] = qwin[i + 1];
      if (kk < 71) qwin[11] = Qs[tc + 12 + kk][nn];
    }
    #pragma unroll
    for (int i = 0; i < 12; i++) Rs[tc + i][nn] = acc[i];
    __syncthreads();   // Rs visible; Qs/Ws reads done

    if (sub + 1 < SUBS) stage(sub + 1);   // overlaps with einsum below

    #pragma unroll
    for (int g4 = 0; g4 < 16; g4++) {
      float4 g = Greg[g4];
      #pragma unroll
      for (int p = 0; p < 6; p++) {
        float4 rv = *reinterpret_cast<const float4*>(&Rs[te + p][g4 * 4]);
        acc_out[p] += rv.x * g.x + rv.y * g.y + rv.z * g.z + rv.w * g.w;
      }
    }
  }

  #pragma unroll
  for (int p = 0; p < 6; p++) {
    int tg = t0 + te + p;           // always < 1440 (30*48 exact)
    Par[(split * TS + tg) * NOUT + oe] = acc_out[p];
  }
}

// ---------------------------------------------------------------------------
// Kernel 4: reduce partials over the 25 n-splits
// ---------------------------------------------------------------------------
__global__ __launch_bounds__(256) void reduce_kernel(
    const float* __restrict__ Par, float* __restrict__ out)
{
  int i = blockIdx.x * 256 + threadIdx.x;
  if (i < TS * NOUT) {
    float s = 0.0f;
    #pragma unroll
    for (int sp = 0; sp < NSPLIT; sp++) s += Par[sp * (TS * NOUT) + i];
    out[i] = s;
  }
}

// ---------------------------------------------------------------------------
extern "C" void kernel_launch(void* const* d_in, const int* in_sizes, int n_in,
                              void* d_out, int out_size, void* d_ws, size_t ws_size,
                              hipStream_t stream)
{
  const float* x_phy  = (const float*)d_in[0];
  const float* ac_all = (const float*)d_in[1];
  // d_in[2] = elev_all (unused by reference)
  const float* topo   = (const float*)d_in[3];
  const float* areas  = (const float*)d_in[4];
  const float* p1     = (const float*)d_in[5];
  const float* p2     = (const float*)d_in[6];
  float* out = (float*)d_out;

  char* ws = (char*)d_ws;
  float* Q   = (float*)(ws);                                  // 46,080,000 B
  float* W   = (float*)(ws + 46080000);                       //  2,304,000 B
  float* Cst = (float*)(ws + 46080000 + 2304000);             //    512,000 B
  float* Par = (float*)(ws + 46080000 + 2304000 + 512000);    //  4,608,000 B

  hipLaunchKernelGGL(precompute_kernel, dim3(32), dim3(256), 0, stream,
                     p1, p2, ac_all, Cst, W);
  hipLaunchKernelGGL(scan_kernel, dim3(NG / 64), dim3(64), 0, stream,
                     x_phy, Cst, Q);
  hipLaunchKernelGGL(route_kernel, dim3(NWG), dim3(256), 0, stream,
                     Q, W, topo, areas, Par);
  hipLaunchKernelGGL(reduce_kernel, dim3((TS * NOUT + 255) / 256), dim3(256), 0, stream,
                     Par, out);
}